// Round 2
// baseline (371.255 us; speedup 1.0000x reference)
//
#include <hip/hip_runtime.h>
#include <stdint.h>
#include <stddef.h>

// Problem constants
// B=2, S=2048, E=1024, H=16, D=64, KV=1, QKV_OUT=1152
#define SEQ   2048
#define EMB   1024
#define NHEAD 16
#define HDIM  64
#define QKVO  1152
#define MTOT  4096   // B*S

typedef __attribute__((ext_vector_type(4))) float f32x4;
typedef __attribute__((ext_vector_type(8))) short short8;  // 8 bf16
typedef __attribute__((ext_vector_type(4))) short s16x4;

__device__ __forceinline__ short f2bf(float f) {
  union { float f; unsigned u; } v; v.f = f;
  unsigned r = v.u + 0x7FFFu + ((v.u >> 16) & 1u);   // RNE
  return (short)(r >> 16);
}

__device__ __forceinline__ void gload16(const void* g, void* l) {
  __builtin_amdgcn_global_load_lds((const __attribute__((address_space(1))) void*)g,
                                   (__attribute__((address_space(3))) void*)l,
                                   16, 0, 0);
}

// ---------------- prep: bf16 casts + rope tables ----------------
#define PX   524288
#define PW1  671744
#define PW2  802816
#define PTOT 811008

__device__ __forceinline__ void cvt8(const float* __restrict__ s, short* __restrict__ d) {
  float4 a = ((const float4*)s)[0];
  float4 b = ((const float4*)s)[1];
  short8 r;
  r[0]=f2bf(a.x); r[1]=f2bf(a.y); r[2]=f2bf(a.z); r[3]=f2bf(a.w);
  r[4]=f2bf(b.x); r[5]=f2bf(b.y); r[6]=f2bf(b.z); r[7]=f2bf(b.w);
  *(short8*)d = r;
}

__global__ __launch_bounds__(256) void prep_kernel(
    const float* __restrict__ x, const float* __restrict__ wqkv, const float* __restrict__ wout,
    short* __restrict__ xb, short* __restrict__ wqkvb, short* __restrict__ woutb,
    float* __restrict__ cost, float* __restrict__ sint) {
  int c = blockIdx.x * 256 + threadIdx.x;
  if (c < PX) {
    cvt8(x + (size_t)c * 8, xb + (size_t)c * 8);
  } else if (c < PW1) {
    int c2 = c - PX;
    cvt8(wqkv + (size_t)c2 * 8, wqkvb + (size_t)c2 * 8);
  } else if (c < PW2) {
    int c2 = c - PW1;
    cvt8(wout + (size_t)c2 * 8, woutb + (size_t)c2 * 8);
  } else if (c < PTOT) {
    int c2 = c - PW2;
    #pragma unroll
    for (int t = 0; t < 8; ++t) {
      int idx = c2 * 8 + t;
      int pos = idx >> 5, i = idx & 31;
      float inv = powf(10000.0f, -(float)i * (1.0f / 32.0f));
      float ang = (float)pos * inv;
      float sv, cv;
      sincosf(ang, &sv, &cv);
      cost[idx] = cv; sint[idx] = sv;
    }
  }
}

// ---------------- shared GEMM mainloop: 128x128 tile, BK=64 ----------------
__device__ __forceinline__ void gemm_mainloop(
    const short* __restrict__ A, const short* __restrict__ Bm,
    int m0, int n0, short* lsA, short* lsB, f32x4 acc[4][4]) {
  const int w = threadIdx.x >> 6, lane = threadIdx.x & 63;
  const int wm = w >> 1, wn = w & 1;
  const int lrow = lane & 15, lk = (lane >> 4) * 8;
  #pragma unroll
  for (int mi = 0; mi < 4; ++mi)
    #pragma unroll
    for (int ni = 0; ni < 4; ++ni)
      acc[mi][ni] = (f32x4){0.f, 0.f, 0.f, 0.f};

  const int srow8 = lane >> 3;
  const int scol = (lane & 7) * 8;

  for (int kt = 0; kt < 1024; kt += 64) {
    #pragma unroll
    for (int ii = 0; ii < 4; ++ii) {
      int seg = w * 4 + ii;
      int row = seg * 8 + srow8;
      gload16(A  + (size_t)(m0 + row) * 1024 + kt + scol, lsA + seg * 512);
      gload16(Bm + (size_t)(n0 + row) * 1024 + kt + scol, lsB + seg * 512);
    }
    __syncthreads();
    #pragma unroll
    for (int ks = 0; ks < 2; ++ks) {
      short8 af[4], bfv[4];
      #pragma unroll
      for (int mi = 0; mi < 4; ++mi)
        af[mi] = *(const short8*)(lsA + (wm * 64 + mi * 16 + lrow) * 64 + lk + ks * 32);
      #pragma unroll
      for (int ni = 0; ni < 4; ++ni)
        bfv[ni] = *(const short8*)(lsB + (wn * 64 + ni * 16 + lrow) * 64 + lk + ks * 32);
      #pragma unroll
      for (int mi = 0; mi < 4; ++mi)
        #pragma unroll
        for (int ni = 0; ni < 4; ++ni)
          acc[mi][ni] = __builtin_amdgcn_mfma_f32_16x16x32_bf16(af[mi], bfv[ni], acc[mi][ni], 0, 0, 0);
    }
    __syncthreads();
  }
}

// ---------------- QKV GEMM + bias + RoPE + scatter ----------------
// q is pre-scaled by 0.125 * log2(e) so attention works in the exp2 domain.
#define QSCALE 0.180336880111124f

__global__ __launch_bounds__(256) void qkv_kernel(
    const short* __restrict__ xb, const short* __restrict__ wb,
    const float* __restrict__ bias, const float* __restrict__ cost, const float* __restrict__ sint,
    short* __restrict__ qbuf, short* __restrict__ kbuf, short* __restrict__ vt) {
  __shared__ __align__(16) short lsA[8192];
  __shared__ __align__(16) short lsB[8192];
  f32x4 acc[4][4];
  const int m0 = blockIdx.x * 128, n0 = blockIdx.y * 128;
  gemm_mainloop(xb, wb, m0, n0, lsA, lsB, acc);

  const int w = threadIdx.x >> 6, lane = threadIdx.x & 63;
  const int wm = w >> 1, wn = w & 1;
  const int colb = n0 + wn * 64 + (lane & 15);
  const int rowb = m0 + wm * 64 + ((lane >> 4) << 2);
  #pragma unroll
  for (int ni = 0; ni < 4; ++ni) {
    const int col = colb + ni * 16;
    const float bv = bias[col];
    #pragma unroll
    for (int mi = 0; mi < 4; ++mi) {
      #pragma unroll
      for (int j = 0; j < 4; ++j) {
        const int m = rowb + mi * 16 + j;
        const int bb = m >> 11, pos = m & 2047;
        float v = acc[mi][ni][j] + bv;
        float vp = __shfl_xor(v, 1);
        float ov;
        if (col < 1088) {
          const int d = (col < 1024) ? (col & 63) : (col - 1024);
          const int i = d >> 1;
          const float cv = cost[pos * 32 + i], sv = sint[pos * 32 + i];
          ov = ((col & 1) == 0) ? (v * cv - vp * sv)
                                : (vp * sv + v * cv);
          if (col < 1024) ov *= QSCALE;
        } else {
          ov = v;
        }
        const short bfo = f2bf(ov);
        if (col < 1024) {
          const int h = col >> 6;
          qbuf[(((size_t)bb * NHEAD + h) * SEQ + pos) * HDIM + (col & 63)] = bfo;
        } else if (col < 1088) {
          kbuf[((size_t)bb * SEQ + pos) * HDIM + (col - 1024)] = bfo;
        } else {
          vt[((size_t)bb * HDIM + (col - 1088)) * SEQ + pos] = bfo;
        }
      }
    }
  }
}

// ---------------- flash attention (causal, MQA) ----------------
// grid (32, 32). 4 waves/block, each wave owns 16 q rows independently.
// KVBLK=64. q pre-scaled by 0.125*log2e; all softmax in exp2 domain.
// PV computed transposed (O^T = V^T * P^T) so per-q rescale/normalize are
// lane-local (C col = lane&15 = q) — no cross-lane shuffles needed.
#define PSTRIDE 72   // shorts per P row (64 + 8 pad -> 2-way-max bank alias)

template<bool MASKED>
__device__ __forceinline__ void attn_tile(
    int kv0, int q0, int qloc, int g, int qg,
    const short* __restrict__ kb_b, const short* __restrict__ vt_b, short* pls,
    short8 qf0, short8 qf1, float& m_run, float& l_run, f32x4 o[4]) {
  // --- QK^T (swapped): st[r] = S^T[kv = kv0+16r+g*4+j][q = q0+qloc]
  const short* kt = kb_b + (size_t)(kv0 + qloc) * HDIM + g * 8;
  f32x4 st[4];
  #pragma unroll
  for (int r = 0; r < 4; ++r) {
    short8 k0 = *(const short8*)(kt + r * 16 * HDIM);
    short8 k1 = *(const short8*)(kt + r * 16 * HDIM + 32);
    f32x4 z = (f32x4){0.f, 0.f, 0.f, 0.f};
    z = __builtin_amdgcn_mfma_f32_16x16x32_bf16(k0, qf0, z, 0, 0, 0);
    z = __builtin_amdgcn_mfma_f32_16x16x32_bf16(k1, qf1, z, 0, 0, 0);
    st[r] = z;
  }
  float s[16];
  #pragma unroll
  for (int r = 0; r < 4; ++r)
    #pragma unroll
    for (int j = 0; j < 4; ++j) {
      if (MASKED) {
        const int kv = kv0 + r * 16 + g * 4 + j;
        s[r * 4 + j] = (kv <= qg) ? st[r][j] : -1.0e38f;
      } else {
        s[r * 4 + j] = st[r][j];
      }
    }
  // --- row max (q = qloc; reduce across the 4 g-lanes)
  float mt = s[0];
  #pragma unroll
  for (int i = 1; i < 16; ++i) mt = fmaxf(mt, s[i]);
  mt = fmaxf(mt, __shfl_xor(mt, 16));
  mt = fmaxf(mt, __shfl_xor(mt, 32));
  // --- defer-max: only rescale when the max grew materially (2^11 headroom)
  if (!__all(mt <= m_run + 11.0f)) {
    const float m_new = fmaxf(m_run, mt);
    const float sc = __builtin_amdgcn_exp2f(m_run - m_new);
    #pragma unroll
    for (int nf = 0; nf < 4; ++nf) o[nf] *= sc;
    l_run *= sc;
    m_run = m_new;
  }
  // --- P = exp2(s - m), row sum
  float p[16], ps = 0.f;
  #pragma unroll
  for (int i = 0; i < 16; ++i) { p[i] = __builtin_amdgcn_exp2f(s[i] - m_run); ps += p[i]; }
  ps += __shfl_xor(ps, 16);
  ps += __shfl_xor(ps, 32);
  l_run += ps;
  // --- P -> LDS row [q][kv0..63] (bf16), wave-private
  #pragma unroll
  for (int r = 0; r < 4; ++r)
    #pragma unroll
    for (int jj = 0; jj < 4; jj += 2) {
      unsigned pk = (unsigned)(unsigned short)f2bf(p[r * 4 + jj]) |
                    ((unsigned)(unsigned short)f2bf(p[r * 4 + jj + 1]) << 16);
      *(unsigned*)(pls + r * 16 + g * 4 + jj) = pk;
    }
  // --- re-read as P^T B-fragments (B[k=kv][col=q]); same layout as A-frag read
  short8 pa0 = *(const short8*)(pls - (g * 4 + 0) + 0);  // placeholder fixed below
  (void)pa0;
  const short* prd = pls;  // row base for q=qloc
  short8 pb0 = *(const short8*)(prd + g * 8);
  short8 pb1 = *(const short8*)(prd + 32 + g * 8);
  // --- PV transposed: O^T[d][q] += V^T[d][kv] * P^T[kv][q]
  const short* vtt = vt_b + kv0 + g * 8;
  #pragma unroll
  for (int nf = 0; nf < 4; ++nf) {
    short8 v0 = *(const short8*)(vtt + (size_t)nf * 16 * SEQ);
    short8 v1 = *(const short8*)(vtt + (size_t)nf * 16 * SEQ + 32);
    o[nf] = __builtin_amdgcn_mfma_f32_16x16x32_bf16(v0, pb0, o[nf], 0, 0, 0);
    o[nf] = __builtin_amdgcn_mfma_f32_16x16x32_bf16(v1, pb1, o[nf], 0, 0, 0);
  }
}

__global__ __launch_bounds__(256, 4) void attn_kernel(
    const short* __restrict__ qb, const short* __restrict__ kb,
    const short* __restrict__ vt, short* __restrict__ ao) {
  __shared__ __align__(16) short plds[4][16][PSTRIDE];
  const int w = threadIdx.x >> 6, lane = threadIdx.x & 63;
  const int bh = blockIdx.y, bb = bh >> 4, h = bh & 15;
  const int q0 = blockIdx.x * 64 + w * 16;
  const int g = lane >> 4, qloc = lane & 15;
  const int qg = q0 + qloc;

  const short* qbase = qb + (((size_t)bb * NHEAD + h) * SEQ + q0 + qloc) * HDIM + g * 8;
  short8 qf0 = *(const short8*)qbase;
  short8 qf1 = *(const short8*)(qbase + 32);

  f32x4 o[4];
  #pragma unroll
  for (int nf = 0; nf < 4; ++nf) o[nf] = (f32x4){0.f, 0.f, 0.f, 0.f};
  float m_run = -1.0e38f, l_run = 0.0f;

  short* pls = &plds[w][qloc][0];
  const short* kb_b = kb + (size_t)bb * SEQ * HDIM;
  const short* vt_b = vt + ((size_t)bb * HDIM + qloc) * SEQ;  // V^T row d=qloc(+nf*16)

  const int nfull = q0 >> 6;   // tiles fully below the diagonal for all 16 rows
  for (int t = 0; t < nfull; ++t)
    attn_tile<false>(t * 64, q0, qloc, g, qg, kb_b, vt_b, pls, qf0, qf1, m_run, l_run, o);
  attn_tile<true>(nfull * 64, q0, qloc, g, qg, kb_b, vt_b, pls, qf0, qf1, m_run, l_run, o);

  const float inv = 1.0f / l_run;   // l is per-q (lane-local), no shuffle
  const size_t obase = ((size_t)bb * SEQ + q0 + qloc) * EMB + (size_t)h * HDIM + g * 4;
  #pragma unroll
  for (int nf = 0; nf < 4; ++nf) {
    s16x4 pk;
    #pragma unroll
    for (int j = 0; j < 4; ++j) pk[j] = f2bf(o[nf][j] * inv);
    *(s16x4*)(ao + obase + nf * 16) = pk;   // row q, cols h*64 + nf*16 + g*4 + j
  }
}

// ---------------- output GEMM + bias ----------------
__global__ __launch_bounds__(256) void out_kernel(
    const short* __restrict__ ab, const short* __restrict__ wb,
    const float* __restrict__ bias, float* __restrict__ out) {
  __shared__ __align__(16) short lsA[8192];
  __shared__ __align__(16) short lsB[8192];
  f32x4 acc[4][4];
  const int m0 = blockIdx.x * 128, n0 = blockIdx.y * 128;
  gemm_mainloop(ab, wb, m0, n0, lsA, lsB, acc);

  const int w = threadIdx.x >> 6, lane = threadIdx.x & 63;
  const int wm = w >> 1, wn = w & 1;
  const int colb = n0 + wn * 64 + (lane & 15);
  const int rowb = m0 + wm * 64 + ((lane >> 4) << 2);
  #pragma unroll
  for (int ni = 0; ni < 4; ++ni) {
    const int col = colb + ni * 16;
    const float bv = bias[col];
    #pragma unroll
    for (int mi = 0; mi < 4; ++mi)
      #pragma unroll
      for (int j = 0; j < 4; ++j) {
        const int m = rowb + mi * 16 + j;
        out[(size_t)m * EMB + col] = acc[mi][ni][j] + bv;
      }
  }
}

// ---------------- launch ----------------
extern "C" void kernel_launch(void* const* d_in, const int* in_sizes, int n_in,
                              void* d_out, int out_size, void* d_ws, size_t ws_size,
                              hipStream_t stream) {
  const float* x    = (const float*)d_in[0];
  const float* qkvw = (const float*)d_in[1];
  const float* qkvb = (const float*)d_in[2];
  const float* outw = (const float*)d_in[3];
  const float* outb = (const float*)d_in[4];
  float* out = (float*)d_out;
  char* ws = (char*)d_ws;

  short* xb    = (short*)(ws + 0);            // 4096x1024 bf16 — reused as attn_out
  short* wqkvb = (short*)(ws + 8388608);      // 1152x1024 bf16
  short* woutb = (short*)(ws + 10747904);     // 1024x1024 bf16
  float* cost  = (float*)(ws + 12845056);     // 2048x32 f32
  float* sint  = (float*)(ws + 13107200);
  short* qbuf  = (short*)(ws + 13369344);     // [B][H][S][D] bf16, q pre-scaled
  short* kbuf  = (short*)(ws + 21757952);     // [B][S][D] bf16
  short* vtb   = (short*)(ws + 22282240);     // [B][D][S] bf16 (transposed)
  short* aob   = xb;

  prep_kernel<<<3168, 256, 0, stream>>>(x, qkvw, outw, xb, wqkvb, woutb, cost, sint);
  qkv_kernel<<<dim3(32, 9), 256, 0, stream>>>(xb, wqkvb, qkvb, cost, sint, qbuf, kbuf, vtb);
  attn_kernel<<<dim3(32, 32), 256, 0, stream>>>(qbuf, kbuf, vtb, aob);
  out_kernel<<<dim3(32, 8), 256, 0, stream>>>(aob, woutb, outb, out);
}

// Round 4
// 192.135 us; speedup vs baseline: 1.9323x; 1.9323x over previous
//
#include <hip/hip_runtime.h>
#include <stdint.h>
#include <stddef.h>

// Problem constants
// B=2, S=2048, E=1024, H=16, D=64, KV=1, QKV_OUT=1152
#define SEQ   2048
#define EMB   1024
#define NHEAD 16
#define HDIM  64
#define QKVO  1152
#define MTOT  4096   // B*S

typedef __attribute__((ext_vector_type(4))) float f32x4;
typedef __attribute__((ext_vector_type(8))) short short8;  // 8 bf16
typedef __attribute__((ext_vector_type(4))) short s16x4;

__device__ __forceinline__ short f2bf(float f) {
  union { float f; unsigned u; } v; v.f = f;
  unsigned r = v.u + 0x7FFFu + ((v.u >> 16) & 1u);   // RNE
  return (short)(r >> 16);
}

__device__ __forceinline__ void gload16(const void* g, void* l) {
  __builtin_amdgcn_global_load_lds((const __attribute__((address_space(1))) void*)g,
                                   (__attribute__((address_space(3))) void*)l,
                                   16, 0, 0);
}

// ---------------- prep: bf16 casts + rope tables ----------------
#define PX   524288
#define PW1  671744
#define PW2  802816
#define PTOT 811008

__device__ __forceinline__ void cvt8(const float* __restrict__ s, short* __restrict__ d) {
  float4 a = ((const float4*)s)[0];
  float4 b = ((const float4*)s)[1];
  short8 r;
  r[0]=f2bf(a.x); r[1]=f2bf(a.y); r[2]=f2bf(a.z); r[3]=f2bf(a.w);
  r[4]=f2bf(b.x); r[5]=f2bf(b.y); r[6]=f2bf(b.z); r[7]=f2bf(b.w);
  *(short8*)d = r;
}

__global__ __launch_bounds__(256) void prep_kernel(
    const float* __restrict__ x, const float* __restrict__ wqkv, const float* __restrict__ wout,
    short* __restrict__ xb, short* __restrict__ wqkvb, short* __restrict__ woutb,
    float* __restrict__ cost, float* __restrict__ sint) {
  int c = blockIdx.x * 256 + threadIdx.x;
  if (c < PX) {
    cvt8(x + (size_t)c * 8, xb + (size_t)c * 8);
  } else if (c < PW1) {
    int c2 = c - PX;
    cvt8(wqkv + (size_t)c2 * 8, wqkvb + (size_t)c2 * 8);
  } else if (c < PW2) {
    int c2 = c - PW1;
    cvt8(wout + (size_t)c2 * 8, woutb + (size_t)c2 * 8);
  } else if (c < PTOT) {
    int c2 = c - PW2;
    #pragma unroll
    for (int t = 0; t < 8; ++t) {
      int idx = c2 * 8 + t;
      int pos = idx >> 5, i = idx & 31;
      float inv = powf(10000.0f, -(float)i * (1.0f / 32.0f));
      float ang = (float)pos * inv;
      float sv, cv;
      sincosf(ang, &sv, &cv);
      cost[idx] = cv; sint[idx] = sv;
    }
  }
}

// ---------------- shared GEMM mainloop: 128x128 tile, BK=64 ----------------
__device__ __forceinline__ void gemm_mainloop(
    const short* __restrict__ A, const short* __restrict__ Bm,
    int m0, int n0, short* lsA, short* lsB, f32x4 acc[4][4]) {
  const int w = threadIdx.x >> 6, lane = threadIdx.x & 63;
  const int wm = w >> 1, wn = w & 1;
  const int lrow = lane & 15, lk = (lane >> 4) * 8;
  #pragma unroll
  for (int mi = 0; mi < 4; ++mi)
    #pragma unroll
    for (int ni = 0; ni < 4; ++ni)
      acc[mi][ni] = (f32x4){0.f, 0.f, 0.f, 0.f};

  const int srow8 = lane >> 3;
  const int scol = (lane & 7) * 8;

  for (int kt = 0; kt < 1024; kt += 64) {
    #pragma unroll
    for (int ii = 0; ii < 4; ++ii) {
      int seg = w * 4 + ii;
      int row = seg * 8 + srow8;
      gload16(A  + (size_t)(m0 + row) * 1024 + kt + scol, lsA + seg * 512);
      gload16(Bm + (size_t)(n0 + row) * 1024 + kt + scol, lsB + seg * 512);
    }
    __syncthreads();
    #pragma unroll
    for (int ks = 0; ks < 2; ++ks) {
      short8 af[4], bfv[4];
      #pragma unroll
      for (int mi = 0; mi < 4; ++mi)
        af[mi] = *(const short8*)(lsA + (wm * 64 + mi * 16 + lrow) * 64 + lk + ks * 32);
      #pragma unroll
      for (int ni = 0; ni < 4; ++ni)
        bfv[ni] = *(const short8*)(lsB + (wn * 64 + ni * 16 + lrow) * 64 + lk + ks * 32);
      #pragma unroll
      for (int mi = 0; mi < 4; ++mi)
        #pragma unroll
        for (int ni = 0; ni < 4; ++ni)
          acc[mi][ni] = __builtin_amdgcn_mfma_f32_16x16x32_bf16(af[mi], bfv[ni], acc[mi][ni], 0, 0, 0);
    }
    __syncthreads();
  }
}

// ---------------- QKV GEMM + bias + RoPE + scatter ----------------
// q is pre-scaled by 0.125 * log2(e) so attention works in the exp2 domain.
#define QSCALE 0.180336880111124f

__global__ __launch_bounds__(256) void qkv_kernel(
    const short* __restrict__ xb, const short* __restrict__ wb,
    const float* __restrict__ bias, const float* __restrict__ cost, const float* __restrict__ sint,
    short* __restrict__ qbuf, short* __restrict__ kbuf, short* __restrict__ vt) {
  __shared__ __align__(16) short lsA[8192];
  __shared__ __align__(16) short lsB[8192];
  f32x4 acc[4][4];
  const int m0 = blockIdx.x * 128, n0 = blockIdx.y * 128;
  gemm_mainloop(xb, wb, m0, n0, lsA, lsB, acc);

  const int w = threadIdx.x >> 6, lane = threadIdx.x & 63;
  const int wm = w >> 1, wn = w & 1;
  const int colb = n0 + wn * 64 + (lane & 15);
  const int rowb = m0 + wm * 64 + ((lane >> 4) << 2);
  #pragma unroll
  for (int ni = 0; ni < 4; ++ni) {
    const int col = colb + ni * 16;
    const float bv = bias[col];
    #pragma unroll
    for (int mi = 0; mi < 4; ++mi) {
      #pragma unroll
      for (int j = 0; j < 4; ++j) {
        const int m = rowb + mi * 16 + j;
        const int bb = m >> 11, pos = m & 2047;
        float v = acc[mi][ni][j] + bv;
        float vp = __shfl_xor(v, 1);
        float ov;
        if (col < 1088) {
          const int d = (col < 1024) ? (col & 63) : (col - 1024);
          const int i = d >> 1;
          const float cv = cost[pos * 32 + i], sv = sint[pos * 32 + i];
          ov = ((col & 1) == 0) ? (v * cv - vp * sv)
                                : (vp * sv + v * cv);
          if (col < 1024) ov *= QSCALE;
        } else {
          ov = v;
        }
        const short bfo = f2bf(ov);
        if (col < 1024) {
          const int h = col >> 6;
          qbuf[(((size_t)bb * NHEAD + h) * SEQ + pos) * HDIM + (col & 63)] = bfo;
        } else if (col < 1088) {
          kbuf[((size_t)bb * SEQ + pos) * HDIM + (col - 1024)] = bfo;
        } else {
          vt[((size_t)bb * HDIM + (col - 1088)) * SEQ + pos] = bfo;
        }
      }
    }
  }
}

// ---------------- flash attention (causal, MQA) ----------------
// grid (32 bh, 32 qchunk'), qchunk = 31 - blockIdx.y (heavy blocks first).
// 4 waves/block, each wave owns 16 q rows; all waves share the SAME kv tiles.
// K/V staged blockwide into XOR-swizzled LDS via global_load_lds, double
// buffered with counted vmcnt (T3/T4 2-phase); softmax in exp2 domain;
// PV transposed (O^T = V^T * P^T) so rescale/normalize are lane-local.
#define PSTRIDE 72

__device__ __forceinline__ void stage_kv(
    const short* __restrict__ kb_b, const short* __restrict__ vt_b, int kv0,
    short* Kb, short* Vb, int tid) {
  // K tile: rows kv0..kv0+63 of [S][64]; V^T tile: rows d=0..63, cols kv0..+63.
  // LDS chunk ci holds tile (r = ci>>3, 16B col chunk ci&7); global source col
  // is XOR-swizzled so linear LDS writes land swizzled (involution on read).
  #pragma unroll
  for (int rd = 0; rd < 2; ++rd) {
    const int ci = rd * 256 + tid;
    const int r = ci >> 3;
    const int cs = ((ci & 7) * 8) ^ ((r & 7) << 3);   // in shorts
    gload16(kb_b + (size_t)(kv0 + r) * HDIM + cs, Kb + ci * 8);
  }
  #pragma unroll
  for (int rd = 0; rd < 2; ++rd) {
    const int ci = rd * 256 + tid;
    const int r = ci >> 3;
    const int cs = ((ci & 7) * 8) ^ ((r & 7) << 3);
    gload16(vt_b + (size_t)r * SEQ + kv0 + cs, Vb + ci * 8);
  }
}

template<bool MASKED>
__device__ __forceinline__ void attn_tile(
    const short* __restrict__ Kb, const short* __restrict__ Vb,
    int kv0, int qg, int g, int sadr0, int sadr1,
    short* pls,
    short8 qf0, short8 qf1, float& m_run, float& l_run, f32x4 o[4]) {
  // --- QK^T (swapped): st[r] = S^T[kv = kv0+16r+g*4+j][q]
  f32x4 st[4];
  #pragma unroll
  for (int r = 0; r < 4; ++r) {
    short8 k0 = *(const short8*)(Kb + sadr0 + r * 1024);
    short8 k1 = *(const short8*)(Kb + sadr1 + r * 1024);
    f32x4 z = (f32x4){0.f, 0.f, 0.f, 0.f};
    z = __builtin_amdgcn_mfma_f32_16x16x32_bf16(k0, qf0, z, 0, 0, 0);
    z = __builtin_amdgcn_mfma_f32_16x16x32_bf16(k1, qf1, z, 0, 0, 0);
    st[r] = z;
  }
  float s[16];
  #pragma unroll
  for (int r = 0; r < 4; ++r)
    #pragma unroll
    for (int j = 0; j < 4; ++j) {
      if (MASKED) {
        const int kv = kv0 + r * 16 + g * 4 + j;
        s[r * 4 + j] = (kv <= qg) ? st[r][j] : -1.0e38f;
      } else {
        s[r * 4 + j] = st[r][j];
      }
    }
  float mt = s[0];
  #pragma unroll
  for (int i = 1; i < 16; ++i) mt = fmaxf(mt, s[i]);
  mt = fmaxf(mt, __shfl_xor(mt, 16));
  mt = fmaxf(mt, __shfl_xor(mt, 32));
  if (!__all(mt <= m_run + 11.0f)) {       // defer-max (T13)
    const float m_new = fmaxf(m_run, mt);
    const float sc = __builtin_amdgcn_exp2f(m_run - m_new);
    #pragma unroll
    for (int nf = 0; nf < 4; ++nf) o[nf] *= sc;
    l_run *= sc;
    m_run = m_new;
  }
  float p[16], ps = 0.f;
  #pragma unroll
  for (int i = 0; i < 16; ++i) { p[i] = __builtin_amdgcn_exp2f(s[i] - m_run); ps += p[i]; }
  ps += __shfl_xor(ps, 16);
  ps += __shfl_xor(ps, 32);
  l_run += ps;
  // --- P -> LDS row (bf16), wave-private; re-read as P^T B-fragments
  #pragma unroll
  for (int r = 0; r < 4; ++r)
    #pragma unroll
    for (int jj = 0; jj < 4; jj += 2) {
      unsigned pk = (unsigned)(unsigned short)f2bf(p[r * 4 + jj]) |
                    ((unsigned)(unsigned short)f2bf(p[r * 4 + jj + 1]) << 16);
      *(unsigned*)(pls + r * 16 + g * 4 + jj) = pk;
    }
  short8 pb0 = *(const short8*)(pls + g * 8);
  short8 pb1 = *(const short8*)(pls + 32 + g * 8);
  // --- PV transposed: O^T[d][q] += V^T[d][kv] * P^T[kv][q]
  #pragma unroll
  for (int nf = 0; nf < 4; ++nf) {
    short8 v0 = *(const short8*)(Vb + sadr0 + nf * 1024);
    short8 v1 = *(const short8*)(Vb + sadr1 + nf * 1024);
    o[nf] = __builtin_amdgcn_mfma_f32_16x16x32_bf16(v0, pb0, o[nf], 0, 0, 0);
    o[nf] = __builtin_amdgcn_mfma_f32_16x16x32_bf16(v1, pb1, o[nf], 0, 0, 0);
  }
}

__global__ __launch_bounds__(256, 3) void attn_kernel(
    const short* __restrict__ qb, const short* __restrict__ kb,
    const short* __restrict__ vt, short* __restrict__ ao) {
  __shared__ __align__(16) short Kls[2][4096];
  __shared__ __align__(16) short Vls[2][4096];
  __shared__ __align__(16) short plds[4][16][PSTRIDE];
  const int tid = threadIdx.x, w = tid >> 6, lane = tid & 63;
  const int bh = blockIdx.x, bb = bh >> 4, h = bh & 15;
  const int qchunk = 31 - blockIdx.y;          // heavy blocks dispatch first
  const int q0 = qchunk * 64 + w * 16;
  const int g = lane >> 4, qloc = lane & 15;
  const int qg = q0 + qloc;

  const short* kb_b = kb + (size_t)bb * SEQ * HDIM;
  const short* vt_b = vt + (size_t)bb * HDIM * SEQ;

  const short* qbase = qb + (((size_t)bb * NHEAD + h) * SEQ + q0 + qloc) * HDIM + g * 8;
  short8 qf0 = *(const short8*)qbase;
  short8 qf1 = *(const short8*)(qbase + 32);

  f32x4 o[4];
  #pragma unroll
  for (int nf = 0; nf < 4; ++nf) o[nf] = (f32x4){0.f, 0.f, 0.f, 0.f};
  float m_run = -1.0e38f, l_run = 0.0f;

  short* pls = &plds[w][qloc][0];
  // swizzled per-lane fragment addresses (shorts): row=qloc(+16r), col=g*8(+32)
  const int swm = (qloc & 7) << 3;
  const int sadr0 = qloc * 64 + ((g * 8) ^ swm);
  const int sadr1 = qloc * 64 + ((g * 8 + 32) ^ swm);

  stage_kv(kb_b, vt_b, 0, Kls[0], Vls[0], tid);
  const int nt = qchunk + 1;
  for (int t = 0; t < nt; ++t) {
    if (t + 1 < nt) {
      stage_kv(kb_b, vt_b, (t + 1) * 64, Kls[(t + 1) & 1], Vls[(t + 1) & 1], tid);
      asm volatile("s_waitcnt vmcnt(4)" ::: "memory");   // tile t landed; t+1 in flight
    } else {
      asm volatile("s_waitcnt vmcnt(0)" ::: "memory");
    }
    __builtin_amdgcn_sched_barrier(0);
    __builtin_amdgcn_s_barrier();
    __builtin_amdgcn_sched_barrier(0);
    const short* Kb = Kls[t & 1];
    const short* Vb = Vls[t & 1];
    if (t + 1 < nt)
      attn_tile<false>(Kb, Vb, t * 64, qg, g, sadr0, sadr1, pls, qf0, qf1, m_run, l_run, o);
    else
      attn_tile<true>(Kb, Vb, t * 64, qg, g, sadr0, sadr1, pls, qf0, qf1, m_run, l_run, o);
    __builtin_amdgcn_sched_barrier(0);
    __builtin_amdgcn_s_barrier();   // all waves done reading buf[t&1] before t+2 stage
  }

  const float inv = 1.0f / l_run;   // l is per-q (lane-local)
  const size_t obase = ((size_t)bb * SEQ + q0 + qloc) * EMB + (size_t)h * HDIM + g * 4;
  #pragma unroll
  for (int nf = 0; nf < 4; ++nf) {
    s16x4 pk;
    #pragma unroll
    for (int j = 0; j < 4; ++j) pk[j] = f2bf(o[nf][j] * inv);
    *(s16x4*)(ao + obase + nf * 16) = pk;
  }
}

// ---------------- output GEMM + bias ----------------
__global__ __launch_bounds__(256) void out_kernel(
    const short* __restrict__ ab, const short* __restrict__ wb,
    const float* __restrict__ bias, float* __restrict__ out) {
  __shared__ __align__(16) short lsA[8192];
  __shared__ __align__(16) short lsB[8192];
  f32x4 acc[4][4];
  const int m0 = blockIdx.x * 128, n0 = blockIdx.y * 128;
  gemm_mainloop(ab, wb, m0, n0, lsA, lsB, acc);

  const int w = threadIdx.x >> 6, lane = threadIdx.x & 63;
  const int wm = w >> 1, wn = w & 1;
  const int colb = n0 + wn * 64 + (lane & 15);
  const int rowb = m0 + wm * 64 + ((lane >> 4) << 2);
  #pragma unroll
  for (int ni = 0; ni < 4; ++ni) {
    const int col = colb + ni * 16;
    const float bv = bias[col];
    #pragma unroll
    for (int mi = 0; mi < 4; ++mi)
      #pragma unroll
      for (int j = 0; j < 4; ++j) {
        const int m = rowb + mi * 16 + j;
        out[(size_t)m * EMB + col] = acc[mi][ni][j] + bv;
      }
  }
}

// ---------------- launch ----------------
extern "C" void kernel_launch(void* const* d_in, const int* in_sizes, int n_in,
                              void* d_out, int out_size, void* d_ws, size_t ws_size,
                              hipStream_t stream) {
  const float* x    = (const float*)d_in[0];
  const float* qkvw = (const float*)d_in[1];
  const float* qkvb = (const float*)d_in[2];
  const float* outw = (const float*)d_in[3];
  const float* outb = (const float*)d_in[4];
  float* out = (float*)d_out;
  char* ws = (char*)d_ws;

  short* xb    = (short*)(ws + 0);            // 4096x1024 bf16 — reused as attn_out
  short* wqkvb = (short*)(ws + 8388608);      // 1152x1024 bf16
  short* woutb = (short*)(ws + 10747904);     // 1024x1024 bf16
  float* cost  = (float*)(ws + 12845056);     // 2048x32 f32
  float* sint  = (float*)(ws + 13107200);
  short* qbuf  = (short*)(ws + 13369344);     // [B][H][S][D] bf16, q pre-scaled
  short* kbuf  = (short*)(ws + 21757952);     // [B][S][D] bf16
  short* vtb   = (short*)(ws + 22282240);     // [B][D][S] bf16 (transposed)
  short* aob   = xb;

  prep_kernel<<<3168, 256, 0, stream>>>(x, qkvw, outw, xb, wqkvb, woutb, cost, sint);
  qkv_kernel<<<dim3(32, 9), 256, 0, stream>>>(xb, wqkvb, qkvb, cost, sint, qbuf, kbuf, vtb);
  attn_kernel<<<dim3(32, 32), 256, 0, stream>>>(qbuf, kbuf, vtb, aob);
  out_kernel<<<dim3(32, 8), 256, 0, stream>>>(aob, woutb, outb, out);
}

// Round 5
// 172.049 us; speedup vs baseline: 2.1578x; 1.1167x over previous
//
#include <hip/hip_runtime.h>
#include <stdint.h>
#include <stddef.h>

// B=2, S=2048, E=1024, H=16, D=64, KV=1, QKV_OUT=1152
#define SEQ   2048
#define EMB   1024
#define NHEAD 16
#define HDIM  64
#define QKVO  1152
#define MTOT  4096

typedef __attribute__((ext_vector_type(4))) float f32x4;
typedef __attribute__((ext_vector_type(8))) short short8;  // 8 bf16
typedef __attribute__((ext_vector_type(4))) short s16x4;

__device__ __forceinline__ short f2bf(float f) {
  union { float f; unsigned u; } v; v.f = f;
  unsigned r = v.u + 0x7FFFu + ((v.u >> 16) & 1u);   // RNE
  return (short)(r >> 16);
}

__device__ __forceinline__ unsigned cvtpk_bf16(float lo, float hi) {
  unsigned r;
  asm("v_cvt_pk_bf16_f32 %0, %1, %2" : "=v"(r) : "v"(lo), "v"(hi));
  return r;
}

__device__ __forceinline__ void gload16(const void* g, void* l) {
  __builtin_amdgcn_global_load_lds((const __attribute__((address_space(1))) void*)g,
                                   (__attribute__((address_space(3))) void*)l,
                                   16, 0, 0);
}

// ---------------- prep: bf16 casts + rope tables ----------------
#define PX   524288
#define PW1  671744
#define PW2  802816
#define PTOT 811008

__device__ __forceinline__ void cvt8(const float* __restrict__ s, short* __restrict__ d) {
  float4 a = ((const float4*)s)[0];
  float4 b = ((const float4*)s)[1];
  short8 r;
  r[0]=f2bf(a.x); r[1]=f2bf(a.y); r[2]=f2bf(a.z); r[3]=f2bf(a.w);
  r[4]=f2bf(b.x); r[5]=f2bf(b.y); r[6]=f2bf(b.z); r[7]=f2bf(b.w);
  *(short8*)d = r;
}

__global__ __launch_bounds__(256) void prep_kernel(
    const float* __restrict__ x, const float* __restrict__ wqkv, const float* __restrict__ wout,
    short* __restrict__ xb, short* __restrict__ wqkvb, short* __restrict__ woutb,
    float* __restrict__ cost, float* __restrict__ sint) {
  int c = blockIdx.x * 256 + threadIdx.x;
  if (c < PX) {
    cvt8(x + (size_t)c * 8, xb + (size_t)c * 8);
  } else if (c < PW1) {
    int c2 = c - PX;
    cvt8(wqkv + (size_t)c2 * 8, wqkvb + (size_t)c2 * 8);
  } else if (c < PW2) {
    int c2 = c - PW1;
    cvt8(wout + (size_t)c2 * 8, woutb + (size_t)c2 * 8);
  } else if (c < PTOT) {
    int c2 = c - PW2;
    #pragma unroll
    for (int t = 0; t < 8; ++t) {
      int idx = c2 * 8 + t;
      int pos = idx >> 5, i = idx & 31;
      float inv = powf(10000.0f, -(float)i * (1.0f / 32.0f));
      float ang = (float)pos * inv;
      float sv, cv;
      sincosf(ang, &sv, &cv);
      cost[idx] = cv; sint[idx] = sv;
    }
  }
}

// ---------------- shared GEMM mainloop: 128x128 tile, BK=64 ----------------
// Double-buffered LDS (2 x [A 8192 | B 8192] shorts), counted vmcnt(8),
// raw barriers (T3/T4 min 2-phase). LDS XOR-swizzled via pre-swizzled global
// source col (rule #21 both-sides involution): col ^= (row&7)<<3 (shorts).
__device__ __forceinline__ void gemm_mainloop(
    const short* __restrict__ A, const short* __restrict__ Bm,
    int m0, int n0, short* ls, f32x4 acc[4][4]) {
  const int w = threadIdx.x >> 6, lane = threadIdx.x & 63;
  const int wm = w >> 1, wn = w & 1;
  const int lrow = lane & 15, lk = (lane >> 4) * 8;
  #pragma unroll
  for (int mi = 0; mi < 4; ++mi)
    #pragma unroll
    for (int ni = 0; ni < 4; ++ni)
      acc[mi][ni] = (f32x4){0.f, 0.f, 0.f, 0.f};

  const int srow8 = lane >> 3;                       // row within 8-row segment
  const int scol = ((lane & 7) * 8) ^ (srow8 << 3);  // swizzled source col (shorts)
  const int rswz = (lrow & 7) << 3;                  // read-side swizzle

  #define GSTAGE(buf, kt)                                                     \
    _Pragma("unroll")                                                         \
    for (int ii = 0; ii < 4; ++ii) {                                          \
      int seg = w * 4 + ii;                                                   \
      int row = seg * 8 + srow8;                                              \
      gload16(A  + (size_t)(m0 + row) * 1024 + (kt) + scol, (buf) + seg * 512);\
      gload16(Bm + (size_t)(n0 + row) * 1024 + (kt) + scol, (buf) + 8192 + seg * 512);\
    }

  GSTAGE(ls, 0);
  for (int t = 0; t < 16; ++t) {
    short* cur = ls + (t & 1) * 16384;
    short* nxt = ls + ((t + 1) & 1) * 16384;
    if (t < 15) {
      GSTAGE(nxt, (t + 1) * 64);
      asm volatile("s_waitcnt vmcnt(8)" ::: "memory");   // tile t landed; t+1 in flight
    } else {
      asm volatile("s_waitcnt vmcnt(0)" ::: "memory");
    }
    __builtin_amdgcn_sched_barrier(0);
    __builtin_amdgcn_s_barrier();
    __builtin_amdgcn_sched_barrier(0);
    #pragma unroll
    for (int ks = 0; ks < 2; ++ks) {
      short8 af[4], bfv[4];
      #pragma unroll
      for (int mi = 0; mi < 4; ++mi)
        af[mi] = *(const short8*)(cur + (wm * 64 + mi * 16 + lrow) * 64 + ((lk + ks * 32) ^ rswz));
      #pragma unroll
      for (int ni = 0; ni < 4; ++ni)
        bfv[ni] = *(const short8*)(cur + 8192 + (wn * 64 + ni * 16 + lrow) * 64 + ((lk + ks * 32) ^ rswz));
      #pragma unroll
      for (int mi = 0; mi < 4; ++mi)
        #pragma unroll
        for (int ni = 0; ni < 4; ++ni)
          acc[mi][ni] = __builtin_amdgcn_mfma_f32_16x16x32_bf16(af[mi], bfv[ni], acc[mi][ni], 0, 0, 0);
    }
    __builtin_amdgcn_sched_barrier(0);
    __builtin_amdgcn_s_barrier();   // all waves done with cur before t+2 restage
  }
  #undef GSTAGE
}

// ---------------- QKV GEMM + bias + RoPE + scatter ----------------
#define QSCALE 0.180336880111124f   // 0.125 * log2(e)

__global__ __launch_bounds__(256, 2) void qkv_kernel(
    const short* __restrict__ xb, const short* __restrict__ wb,
    const float* __restrict__ bias, const float* __restrict__ cost, const float* __restrict__ sint,
    short* __restrict__ qbuf, short* __restrict__ kbuf, short* __restrict__ vt) {
  __shared__ __align__(16) short ls[32768];
  f32x4 acc[4][4];
  const int m0 = blockIdx.x * 128, n0 = blockIdx.y * 128;
  gemm_mainloop(xb, wb, m0, n0, ls, acc);

  const int w = threadIdx.x >> 6, lane = threadIdx.x & 63;
  const int wm = w >> 1, wn = w & 1;
  const int colb = n0 + wn * 64 + (lane & 15);
  const int rowb = m0 + wm * 64 + ((lane >> 4) << 2);
  #pragma unroll
  for (int ni = 0; ni < 4; ++ni) {
    const int col = colb + ni * 16;
    const float bv = bias[col];
    #pragma unroll
    for (int mi = 0; mi < 4; ++mi) {
      #pragma unroll
      for (int j = 0; j < 4; ++j) {
        const int m = rowb + mi * 16 + j;
        const int bb = m >> 11, pos = m & 2047;
        float v = acc[mi][ni][j] + bv;
        float vp = __shfl_xor(v, 1);
        float ov;
        if (col < 1088) {
          const int d = (col < 1024) ? (col & 63) : (col - 1024);
          const int i = d >> 1;
          const float cv = cost[pos * 32 + i], sv = sint[pos * 32 + i];
          ov = ((col & 1) == 0) ? (v * cv - vp * sv)
                                : (vp * sv + v * cv);
          if (col < 1024) ov *= QSCALE;
        } else {
          ov = v;
        }
        const short bfo = f2bf(ov);
        if (col < 1024) {
          const int h = col >> 6;
          qbuf[(((size_t)bb * NHEAD + h) * SEQ + pos) * HDIM + (col & 63)] = bfo;
        } else if (col < 1088) {
          kbuf[((size_t)bb * SEQ + pos) * HDIM + (col - 1024)] = bfo;
        } else {
          vt[((size_t)bb * HDIM + (col - 1088)) * SEQ + pos] = bfo;
        }
      }
    }
  }
}

// ---------------- flash attention (causal, MQA) ----------------
// grid (32 bh, 32 y). qchunk map {b,15-b,16+b,31-b} makes each CU's 4
// resident blocks sum to exactly 66 kv-tiles. 4 waves/block, 16 q rows/wave;
// K/V staged blockwide (XOR-swizzled, global_load_lds, dbuf, counted vmcnt);
// softmax in exp2 domain; PV transposed -> rescale/normalize lane-local.
template<bool MASKED>
__device__ __forceinline__ void attn_tile(
    const short* __restrict__ Kb, const short* __restrict__ Vb,
    int kv0, int qg, int g, int sadr0, int sadr1, int pswz,
    short* pls,
    short8 qf0, short8 qf1, float& m_run, float& l_run, f32x4 o[4]) {
  // --- QK^T (swapped): st[r] = S^T[kv = kv0+16r+g*4+j][q]
  f32x4 st[4];
  __builtin_amdgcn_s_setprio(1);
  #pragma unroll
  for (int r = 0; r < 4; ++r) {
    short8 k0 = *(const short8*)(Kb + sadr0 + r * 1024);
    short8 k1 = *(const short8*)(Kb + sadr1 + r * 1024);
    f32x4 z = (f32x4){0.f, 0.f, 0.f, 0.f};
    z = __builtin_amdgcn_mfma_f32_16x16x32_bf16(k0, qf0, z, 0, 0, 0);
    z = __builtin_amdgcn_mfma_f32_16x16x32_bf16(k1, qf1, z, 0, 0, 0);
    st[r] = z;
  }
  __builtin_amdgcn_s_setprio(0);
  float s[16];
  #pragma unroll
  for (int r = 0; r < 4; ++r)
    #pragma unroll
    for (int j = 0; j < 4; ++j) {
      if (MASKED) {
        const int kv = kv0 + r * 16 + g * 4 + j;
        s[r * 4 + j] = (kv <= qg) ? st[r][j] : -1.0e38f;
      } else {
        s[r * 4 + j] = st[r][j];
      }
    }
  // max tree (max3-friendly triples, depth 3)
  float a0 = fmaxf(fmaxf(s[0], s[1]), s[2]);
  float a1 = fmaxf(fmaxf(s[3], s[4]), s[5]);
  float a2 = fmaxf(fmaxf(s[6], s[7]), s[8]);
  float a3 = fmaxf(fmaxf(s[9], s[10]), s[11]);
  float a4 = fmaxf(fmaxf(s[12], s[13]), s[14]);
  float b0 = fmaxf(fmaxf(a0, a1), a2);
  float b1 = fmaxf(fmaxf(a3, a4), s[15]);
  float mt = fmaxf(b0, b1);
  mt = fmaxf(mt, __shfl_xor(mt, 16));
  mt = fmaxf(mt, __shfl_xor(mt, 32));
  if (!__all(mt <= m_run + 11.0f)) {       // defer-max (T13)
    const float m_new = fmaxf(m_run, mt);
    const float sc = __builtin_amdgcn_exp2f(m_run - m_new);
    #pragma unroll
    for (int nf = 0; nf < 4; ++nf) o[nf] *= sc;
    l_run *= sc;
    m_run = m_new;
  }
  float p[16], ps = 0.f;
  #pragma unroll
  for (int i = 0; i < 16; ++i) { p[i] = __builtin_amdgcn_exp2f(s[i] - m_run); ps += p[i]; }
  ps += __shfl_xor(ps, 16);
  ps += __shfl_xor(ps, 32);
  l_run += ps;
  // --- P -> LDS row (bf16, cvt_pk, XOR-swizzled col); re-read as P^T B-frags
  #pragma unroll
  for (int r = 0; r < 4; ++r)
    #pragma unroll
    for (int jj = 0; jj < 4; jj += 2) {
      unsigned pk = cvtpk_bf16(p[r * 4 + jj], p[r * 4 + jj + 1]);
      *(unsigned*)(pls + ((r * 16 + g * 4 + jj) ^ pswz)) = pk;
    }
  short8 pb0 = *(const short8*)(pls + ((g * 8) ^ pswz));
  short8 pb1 = *(const short8*)(pls + ((32 + g * 8) ^ pswz));
  // --- PV transposed: O^T[d][q] += V^T[d][kv] * P^T[kv][q]
  __builtin_amdgcn_s_setprio(1);
  #pragma unroll
  for (int nf = 0; nf < 4; ++nf) {
    short8 v0 = *(const short8*)(Vb + sadr0 + nf * 1024);
    short8 v1 = *(const short8*)(Vb + sadr1 + nf * 1024);
    o[nf] = __builtin_amdgcn_mfma_f32_16x16x32_bf16(v0, pb0, o[nf], 0, 0, 0);
    o[nf] = __builtin_amdgcn_mfma_f32_16x16x32_bf16(v1, pb1, o[nf], 0, 0, 0);
  }
  __builtin_amdgcn_s_setprio(0);
}

__device__ __forceinline__ void stage_kv(
    const short* __restrict__ kb_b, const short* __restrict__ vt_b, int kv0,
    short* Kb, short* Vb, int tid) {
  #pragma unroll
  for (int rd = 0; rd < 2; ++rd) {
    const int ci = rd * 256 + tid;
    const int r = ci >> 3;
    const int cs = ((ci & 7) * 8) ^ ((r & 7) << 3);
    gload16(kb_b + (size_t)(kv0 + r) * HDIM + cs, Kb + ci * 8);
  }
  #pragma unroll
  for (int rd = 0; rd < 2; ++rd) {
    const int ci = rd * 256 + tid;
    const int r = ci >> 3;
    const int cs = ((ci & 7) * 8) ^ ((r & 7) << 3);
    gload16(vt_b + (size_t)r * SEQ + kv0 + cs, Vb + ci * 8);
  }
}

__global__ __launch_bounds__(256, 4) void attn_kernel(
    const short* __restrict__ qb, const short* __restrict__ kb,
    const short* __restrict__ vt, short* __restrict__ ao) {
  __shared__ __align__(16) short Kls[2][4096];
  __shared__ __align__(16) short Vls[2][4096];
  __shared__ __align__(16) short plds[4][16][64];   // XOR-swizzled, 40960 B total
  const int tid = threadIdx.x, w = tid >> 6, lane = tid & 63;
  const int bh = blockIdx.x, bb = bh >> 4, h = bh & 15;
  const int yy = blockIdx.y, kk = yy >> 3, bq = yy & 7;
  const int qchunk = (kk == 0) ? bq : (kk == 1) ? (15 - bq)
                   : (kk == 2) ? (16 + bq) : (31 - bq);   // per-CU sum = 66 tiles
  const int q0 = qchunk * 64 + w * 16;
  const int g = lane >> 4, qloc = lane & 15;
  const int qg = q0 + qloc;

  const short* kb_b = kb + (size_t)bb * SEQ * HDIM;
  const short* vt_b = vt + (size_t)bb * HDIM * SEQ;

  const short* qbase = qb + (((size_t)bb * NHEAD + h) * SEQ + q0 + qloc) * HDIM + g * 8;
  short8 qf0 = *(const short8*)qbase;
  short8 qf1 = *(const short8*)(qbase + 32);

  f32x4 o[4];
  #pragma unroll
  for (int nf = 0; nf < 4; ++nf) o[nf] = (f32x4){0.f, 0.f, 0.f, 0.f};
  float m_run = -1.0e38f, l_run = 0.0f;

  short* pls = &plds[w][qloc][0];
  const int pswz = (qloc & 7) << 3;
  const int swm = (qloc & 7) << 3;
  const int sadr0 = qloc * 64 + ((g * 8) ^ swm);
  const int sadr1 = qloc * 64 + ((g * 8 + 32) ^ swm);

  stage_kv(kb_b, vt_b, 0, Kls[0], Vls[0], tid);
  const int nt = qchunk + 1;
  for (int t = 0; t < nt; ++t) {
    if (t + 1 < nt) {
      stage_kv(kb_b, vt_b, (t + 1) * 64, Kls[(t + 1) & 1], Vls[(t + 1) & 1], tid);
      asm volatile("s_waitcnt vmcnt(4)" ::: "memory");
    } else {
      asm volatile("s_waitcnt vmcnt(0)" ::: "memory");
    }
    __builtin_amdgcn_sched_barrier(0);
    __builtin_amdgcn_s_barrier();
    __builtin_amdgcn_sched_barrier(0);
    const short* Kb = Kls[t & 1];
    const short* Vb = Vls[t & 1];
    if (t + 1 < nt)
      attn_tile<false>(Kb, Vb, t * 64, qg, g, sadr0, sadr1, pswz, pls, qf0, qf1, m_run, l_run, o);
    else
      attn_tile<true>(Kb, Vb, t * 64, qg, g, sadr0, sadr1, pswz, pls, qf0, qf1, m_run, l_run, o);
    __builtin_amdgcn_sched_barrier(0);
    __builtin_amdgcn_s_barrier();
  }

  const float inv = 1.0f / l_run;   // per-q, lane-local
  const size_t obase = ((size_t)bb * SEQ + q0 + qloc) * EMB + (size_t)h * HDIM + g * 4;
  #pragma unroll
  for (int nf = 0; nf < 4; ++nf) {
    s16x4 pk;
    #pragma unroll
    for (int j = 0; j < 4; ++j) pk[j] = f2bf(o[nf][j] * inv);
    *(s16x4*)(ao + obase + nf * 16) = pk;
  }
}

// ---------------- output GEMM + bias ----------------
__global__ __launch_bounds__(256, 2) void out_kernel(
    const short* __restrict__ ab, const short* __restrict__ wb,
    const float* __restrict__ bias, float* __restrict__ out) {
  __shared__ __align__(16) short ls[32768];
  f32x4 acc[4][4];
  const int m0 = blockIdx.x * 128, n0 = blockIdx.y * 128;
  gemm_mainloop(ab, wb, m0, n0, ls, acc);

  const int w = threadIdx.x >> 6, lane = threadIdx.x & 63;
  const int wm = w >> 1, wn = w & 1;
  const int colb = n0 + wn * 64 + (lane & 15);
  const int rowb = m0 + wm * 64 + ((lane >> 4) << 2);
  #pragma unroll
  for (int ni = 0; ni < 4; ++ni) {
    const int col = colb + ni * 16;
    const float bv = bias[col];
    #pragma unroll
    for (int mi = 0; mi < 4; ++mi)
      #pragma unroll
      for (int j = 0; j < 4; ++j) {
        const int m = rowb + mi * 16 + j;
        out[(size_t)m * EMB + col] = acc[mi][ni][j] + bv;
      }
  }
}

// ---------------- launch ----------------
extern "C" void kernel_launch(void* const* d_in, const int* in_sizes, int n_in,
                              void* d_out, int out_size, void* d_ws, size_t ws_size,
                              hipStream_t stream) {
  const float* x    = (const float*)d_in[0];
  const float* qkvw = (const float*)d_in[1];
  const float* qkvb = (const float*)d_in[2];
  const float* outw = (const float*)d_in[3];
  const float* outb = (const float*)d_in[4];
  float* out = (float*)d_out;
  char* ws = (char*)d_ws;

  short* xb    = (short*)(ws + 0);            // 4096x1024 bf16 — reused as attn_out
  short* wqkvb = (short*)(ws + 8388608);      // 1152x1024 bf16
  short* woutb = (short*)(ws + 10747904);     // 1024x1024 bf16
  float* cost  = (float*)(ws + 12845056);     // 2048x32 f32
  float* sint  = (float*)(ws + 13107200);
  short* qbuf  = (short*)(ws + 13369344);     // [B][H][S][D] bf16, q pre-scaled
  short* kbuf  = (short*)(ws + 21757952);     // [B][S][D] bf16
  short* vtb   = (short*)(ws + 22282240);     // [B][D][S] bf16 (transposed)
  short* aob   = xb;

  prep_kernel<<<3168, 256, 0, stream>>>(x, qkvw, outw, xb, wqkvb, woutb, cost, sint);
  qkv_kernel<<<dim3(32, 9), 256, 0, stream>>>(xb, wqkvb, qkvb, cost, sint, qbuf, kbuf, vtb);
  attn_kernel<<<dim3(32, 32), 256, 0, stream>>>(qbuf, kbuf, vtb, aob);
  out_kernel<<<dim3(32, 8), 256, 0, stream>>>(aob, woutb, outb, out);
}

// Round 12
// 160.148 us; speedup vs baseline: 2.3182x; 1.0743x over previous
//
#include <hip/hip_runtime.h>
#include <stdint.h>
#include <stddef.h>

// B=2, S=2048, E=1024, H=16, D=64, KV=1, QKV_OUT=1152
#define SEQ   2048
#define EMB   1024
#define NHEAD 16
#define HDIM  64
#define QKVO  1152
#define MTOT  4096

typedef __attribute__((ext_vector_type(4))) float f32x4;
typedef __attribute__((ext_vector_type(8))) short short8;  // 8 bf16
typedef __attribute__((ext_vector_type(4))) short s16x4;

__device__ __forceinline__ short f2bf(float f) {
  union { float f; unsigned u; } v; v.f = f;
  unsigned r = v.u + 0x7FFFu + ((v.u >> 16) & 1u);   // RNE
  return (short)(r >> 16);
}

__device__ __forceinline__ unsigned cvtpk_bf16(float lo, float hi) {
  unsigned r;
  asm("v_cvt_pk_bf16_f32 %0, %1, %2" : "=v"(r) : "v"(lo), "v"(hi));
  return r;
}

__device__ __forceinline__ void gload16(const void* g, void* l) {
  __builtin_amdgcn_global_load_lds((const __attribute__((address_space(1))) void*)g,
                                   (__attribute__((address_space(3))) void*)l,
                                   16, 0, 0);
}

// ---------------- prep: bf16 casts + rope tables ----------------
#define PX   524288
#define PW1  671744
#define PW2  802816
#define PTOT 811008

__device__ __forceinline__ void cvt8(const float* __restrict__ s, short* __restrict__ d) {
  float4 a = ((const float4*)s)[0];
  float4 b = ((const float4*)s)[1];
  short8 r;
  r[0]=f2bf(a.x); r[1]=f2bf(a.y); r[2]=f2bf(a.z); r[3]=f2bf(a.w);
  r[4]=f2bf(b.x); r[5]=f2bf(b.y); r[6]=f2bf(b.z); r[7]=f2bf(b.w);
  *(short8*)d = r;
}

__global__ __launch_bounds__(256) void prep_kernel(
    const float* __restrict__ x, const float* __restrict__ wqkv, const float* __restrict__ wout,
    short* __restrict__ xb, short* __restrict__ wqkvb, short* __restrict__ woutb,
    float* __restrict__ cost, float* __restrict__ sint) {
  int c = blockIdx.x * 256 + threadIdx.x;
  if (c < PX) {
    cvt8(x + (size_t)c * 8, xb + (size_t)c * 8);
  } else if (c < PW1) {
    int c2 = c - PX;
    cvt8(wqkv + (size_t)c2 * 8, wqkvb + (size_t)c2 * 8);
  } else if (c < PW2) {
    int c2 = c - PW1;
    cvt8(wout + (size_t)c2 * 8, woutb + (size_t)c2 * 8);
  } else if (c < PTOT) {
    int c2 = c - PW2;
    #pragma unroll
    for (int t = 0; t < 8; ++t) {
      int idx = c2 * 8 + t;
      int pos = idx >> 5, i = idx & 31;
      float inv = powf(10000.0f, -(float)i * (1.0f / 32.0f));
      float ang = (float)pos * inv;
      float sv, cv;
      sincosf(ang, &sv, &cv);
      cost[idx] = cv; sint[idx] = sv;
    }
  }
}

// ---------------- GEMM mainloop: 64x64 tile, BK=64, 4 waves ----------------
// Occupancy-first shape for small-K GEMMs at ~1 grid-block/CU: 32KB dbuf LDS
// -> 4 blocks/CU (4 waves/SIMD) hides stage latency across waves. Counted
// vmcnt(4) 2-phase pipeline; involution XOR swizzle (col ^= (row&7)<<3).
__device__ __forceinline__ void gstage64(
    const short* __restrict__ A, const short* __restrict__ Bm,
    int m0, int n0, int kt, short* buf, int tid) {
  #pragma unroll
  for (int rd = 0; rd < 2; ++rd) {
    const int ci = rd * 256 + tid;
    const int row = ci >> 3;
    const int sc = ((ci & 7) * 8) ^ ((row & 7) << 3);
    gload16(A  + (size_t)(m0 + row) * 1024 + kt + sc, buf + ci * 8);
    gload16(Bm + (size_t)(n0 + row) * 1024 + kt + sc, buf + 4096 + ci * 8);
  }
}

__device__ __forceinline__ void gemm_mainloop64(
    const short* __restrict__ A, const short* __restrict__ Bm,
    int m0, int n0, short* ls, f32x4 acc[2][2]) {
  const int tid = threadIdx.x, w = tid >> 6, lane = tid & 63;
  const int wm = w >> 1, wn = w & 1;
  const int lrow = lane & 15, lk = (lane >> 4) * 8;
  #pragma unroll
  for (int mi = 0; mi < 2; ++mi)
    #pragma unroll
    for (int ni = 0; ni < 2; ++ni)
      acc[mi][ni] = (f32x4){0.f, 0.f, 0.f, 0.f};
  const int rswz = (lrow & 7) << 3;

  gstage64(A, Bm, m0, n0, 0, ls, tid);
  for (int t = 0; t < 16; ++t) {
    short* cur = ls + (t & 1) * 8192;
    short* nxt = ls + ((t + 1) & 1) * 8192;
    if (t < 15) {
      gstage64(A, Bm, m0, n0, (t + 1) * 64, nxt, tid);
      asm volatile("s_waitcnt vmcnt(4)" ::: "memory");   // tile t landed; t+1 in flight
    } else {
      asm volatile("s_waitcnt vmcnt(0)" ::: "memory");
    }
    __builtin_amdgcn_sched_barrier(0);
    __builtin_amdgcn_s_barrier();
    __builtin_amdgcn_sched_barrier(0);
    #pragma unroll
    for (int ks = 0; ks < 2; ++ks) {
      short8 af[2], bfv[2];
      #pragma unroll
      for (int mi = 0; mi < 2; ++mi) {
        const int row = wm * 32 + mi * 16 + lrow;
        af[mi] = *(const short8*)(cur + row * 64 + ((lk + ks * 32) ^ rswz));
      }
      #pragma unroll
      for (int ni = 0; ni < 2; ++ni) {
        const int row = wn * 32 + ni * 16 + lrow;
        bfv[ni] = *(const short8*)(cur + 4096 + row * 64 + ((lk + ks * 32) ^ rswz));
      }
      #pragma unroll
      for (int mi = 0; mi < 2; ++mi)
        #pragma unroll
        for (int ni = 0; ni < 2; ++ni)
          acc[mi][ni] = __builtin_amdgcn_mfma_f32_16x16x32_bf16(af[mi], bfv[ni], acc[mi][ni], 0, 0, 0);
    }
    __builtin_amdgcn_sched_barrier(0);
    __builtin_amdgcn_s_barrier();   // all waves done with cur before restage
  }
}

// ---------------- QKV GEMM + bias + RoPE + scatter ----------------
#define QSCALE 0.180336880111124f   // 0.125 * log2(e)
#define QKV_NN 18                   // 1152/64 n-tiles

__global__ __launch_bounds__(256, 4) void qkv_kernel(
    const short* __restrict__ xb, const short* __restrict__ wb,
    const float* __restrict__ bias, const float* __restrict__ cost, const float* __restrict__ sint,
    short* __restrict__ qbuf, short* __restrict__ kbuf, short* __restrict__ vt) {
  __shared__ __align__(16) short ls[16384];
  f32x4 acc[2][2];
  const int nwg = 64 * QKV_NN;                       // 1152, %8 == 0
  const int wg = (blockIdx.x & 7) * (nwg >> 3) + (blockIdx.x >> 3);  // XCD swizzle
  const int m0 = (wg / QKV_NN) * 64, n0 = (wg % QKV_NN) * 64;
  gemm_mainloop64(xb, wb, m0, n0, ls, acc);

  const int w = threadIdx.x >> 6, lane = threadIdx.x & 63;
  const int wm = w >> 1, wn = w & 1;
  const int colb = n0 + wn * 32 + (lane & 15);
  const int rowb = m0 + wm * 32 + ((lane >> 4) << 2);
  #pragma unroll
  for (int ni = 0; ni < 2; ++ni) {
    const int col = colb + ni * 16;
    const float bv = bias[col];
    #pragma unroll
    for (int mi = 0; mi < 2; ++mi) {
      #pragma unroll
      for (int j = 0; j < 4; ++j) {
        const int m = rowb + mi * 16 + j;
        const int bb = m >> 11, pos = m & 2047;
        float v = acc[mi][ni][j] + bv;
        float vp = __shfl_xor(v, 1);
        float ov;
        if (col < 1088) {
          const int d = (col < 1024) ? (col & 63) : (col - 1024);
          const int i = d >> 1;
          const float cv = cost[pos * 32 + i], sv = sint[pos * 32 + i];
          ov = ((col & 1) == 0) ? (v * cv - vp * sv)
                                : (vp * sv + v * cv);
          if (col < 1024) ov *= QSCALE;
        } else {
          ov = v;
        }
        const short bfo = f2bf(ov);
        if (col < 1024) {
          const int h = col >> 6;
          qbuf[(((size_t)bb * NHEAD + h) * SEQ + pos) * HDIM + (col & 63)] = bfo;
        } else if (col < 1088) {
          kbuf[((size_t)bb * SEQ + pos) * HDIM + (col - 1024)] = bfo;
        } else {
          vt[((size_t)bb * HDIM + (col - 1088)) * SEQ + pos] = bfo;
        }
      }
    }
  }
}

// ---------------- flash attention (causal, MQA) ----------------
// grid (32 bh, 32 y). qchunk map {b,15-b,16+b,31-b}: each CU's 4 resident
// blocks sum to 66 kv-tiles. 4 waves/block, 16 q rows/wave; K/V staged
// blockwide (XOR-swizzled, global_load_lds, dbuf, counted vmcnt); softmax in
// exp2 domain; PV transposed -> rescale/normalize lane-local.
template<bool MASKED>
__device__ __forceinline__ void attn_tile(
    const short* __restrict__ Kb, const short* __restrict__ Vb,
    int kv0, int qg, int g, int sadr0, int sadr1, int pswz,
    short* pls,
    short8 qf0, short8 qf1, float& m_run, float& l_run, f32x4 o[4]) {
  f32x4 st[4];
  __builtin_amdgcn_s_setprio(1);
  #pragma unroll
  for (int r = 0; r < 4; ++r) {
    short8 k0 = *(const short8*)(Kb + sadr0 + r * 1024);
    short8 k1 = *(const short8*)(Kb + sadr1 + r * 1024);
    f32x4 z = (f32x4){0.f, 0.f, 0.f, 0.f};
    z = __builtin_amdgcn_mfma_f32_16x16x32_bf16(k0, qf0, z, 0, 0, 0);
    z = __builtin_amdgcn_mfma_f32_16x16x32_bf16(k1, qf1, z, 0, 0, 0);
    st[r] = z;
  }
  __builtin_amdgcn_s_setprio(0);
  float s[16];
  #pragma unroll
  for (int r = 0; r < 4; ++r)
    #pragma unroll
    for (int j = 0; j < 4; ++j) {
      if (MASKED) {
        const int kv = kv0 + r * 16 + g * 4 + j;
        s[r * 4 + j] = (kv <= qg) ? st[r][j] : -1.0e38f;
      } else {
        s[r * 4 + j] = st[r][j];
      }
    }
  float a0 = fmaxf(fmaxf(s[0], s[1]), s[2]);
  float a1 = fmaxf(fmaxf(s[3], s[4]), s[5]);
  float a2 = fmaxf(fmaxf(s[6], s[7]), s[8]);
  float a3 = fmaxf(fmaxf(s[9], s[10]), s[11]);
  float a4 = fmaxf(fmaxf(s[12], s[13]), s[14]);
  float b0 = fmaxf(fmaxf(a0, a1), a2);
  float b1 = fmaxf(fmaxf(a3, a4), s[15]);
  float mt = fmaxf(b0, b1);
  mt = fmaxf(mt, __shfl_xor(mt, 16));
  mt = fmaxf(mt, __shfl_xor(mt, 32));
  if (!__all(mt <= m_run + 11.0f)) {       // defer-max (T13)
    const float m_new = fmaxf(m_run, mt);
    const float sc = __builtin_amdgcn_exp2f(m_run - m_new);
    #pragma unroll
    for (int nf = 0; nf < 4; ++nf) o[nf] *= sc;
    l_run *= sc;
    m_run = m_new;
  }
  float p[16], ps = 0.f;
  #pragma unroll
  for (int i = 0; i < 16; ++i) { p[i] = __builtin_amdgcn_exp2f(s[i] - m_run); ps += p[i]; }
  ps += __shfl_xor(ps, 16);
  ps += __shfl_xor(ps, 32);
  l_run += ps;
  #pragma unroll
  for (int r = 0; r < 4; ++r)
    #pragma unroll
    for (int jj = 0; jj < 4; jj += 2) {
      unsigned pk = cvtpk_bf16(p[r * 4 + jj], p[r * 4 + jj + 1]);
      *(unsigned*)(pls + ((r * 16 + g * 4 + jj) ^ pswz)) = pk;
    }
  short8 pb0 = *(const short8*)(pls + ((g * 8) ^ pswz));
  short8 pb1 = *(const short8*)(pls + ((32 + g * 8) ^ pswz));
  __builtin_amdgcn_s_setprio(1);
  #pragma unroll
  for (int nf = 0; nf < 4; ++nf) {
    short8 v0 = *(const short8*)(Vb + sadr0 + nf * 1024);
    short8 v1 = *(const short8*)(Vb + sadr1 + nf * 1024);
    o[nf] = __builtin_amdgcn_mfma_f32_16x16x32_bf16(v0, pb0, o[nf], 0, 0, 0);
    o[nf] = __builtin_amdgcn_mfma_f32_16x16x32_bf16(v1, pb1, o[nf], 0, 0, 0);
  }
  __builtin_amdgcn_s_setprio(0);
}

__device__ __forceinline__ void stage_kv(
    const short* __restrict__ kb_b, const short* __restrict__ vt_b, int kv0,
    short* Kb, short* Vb, int tid) {
  #pragma unroll
  for (int rd = 0; rd < 2; ++rd) {
    const int ci = rd * 256 + tid;
    const int r = ci >> 3;
    const int cs = ((ci & 7) * 8) ^ ((r & 7) << 3);
    gload16(kb_b + (size_t)(kv0 + r) * HDIM + cs, Kb + ci * 8);
  }
  #pragma unroll
  for (int rd = 0; rd < 2; ++rd) {
    const int ci = rd * 256 + tid;
    const int r = ci >> 3;
    const int cs = ((ci & 7) * 8) ^ ((r & 7) << 3);
    gload16(vt_b + (size_t)r * SEQ + kv0 + cs, Vb + ci * 8);
  }
}

__global__ __launch_bounds__(256, 4) void attn_kernel(
    const short* __restrict__ qb, const short* __restrict__ kb,
    const short* __restrict__ vt, short* __restrict__ ao) {
  __shared__ __align__(16) short Kls[2][4096];
  __shared__ __align__(16) short Vls[2][4096];
  __shared__ __align__(16) short plds[4][16][64];
  const int tid = threadIdx.x, w = tid >> 6, lane = tid & 63;
  const int bh = blockIdx.x, bb = bh >> 4, h = bh & 15;
  const int yy = blockIdx.y, kk = yy >> 3, bq = yy & 7;
  const int qchunk = (kk == 0) ? bq : (kk == 1) ? (15 - bq)
                   : (kk == 2) ? (16 + bq) : (31 - bq);
  const int q0 = qchunk * 64 + w * 16;
  const int g = lane >> 4, qloc = lane & 15;
  const int qg = q0 + qloc;

  const short* kb_b = kb + (size_t)bb * SEQ * HDIM;
  const short* vt_b = vt + (size_t)bb * HDIM * SEQ;

  const short* qbase = qb + (((size_t)bb * NHEAD + h) * SEQ + q0 + qloc) * HDIM + g * 8;
  short8 qf0 = *(const short8*)qbase;
  short8 qf1 = *(const short8*)(qbase + 32);

  f32x4 o[4];
  #pragma unroll
  for (int nf = 0; nf < 4; ++nf) o[nf] = (f32x4){0.f, 0.f, 0.f, 0.f};
  float m_run = -1.0e38f, l_run = 0.0f;

  short* pls = &plds[w][qloc][0];
  const int pswz = (qloc & 7) << 3;
  const int swm = (qloc & 7) << 3;
  const int sadr0 = qloc * 64 + ((g * 8) ^ swm);
  const int sadr1 = qloc * 64 + ((g * 8 + 32) ^ swm);

  stage_kv(kb_b, vt_b, 0, Kls[0], Vls[0], tid);
  const int nt = qchunk + 1;
  for (int t = 0; t < nt; ++t) {
    if (t + 1 < nt) {
      stage_kv(kb_b, vt_b, (t + 1) * 64, Kls[(t + 1) & 1], Vls[(t + 1) & 1], tid);
      asm volatile("s_waitcnt vmcnt(4)" ::: "memory");
    } else {
      asm volatile("s_waitcnt vmcnt(0)" ::: "memory");
    }
    __builtin_amdgcn_sched_barrier(0);
    __builtin_amdgcn_s_barrier();
    __builtin_amdgcn_sched_barrier(0);
    const short* Kb = Kls[t & 1];
    const short* Vb = Vls[t & 1];
    if (t + 1 < nt)
      attn_tile<false>(Kb, Vb, t * 64, qg, g, sadr0, sadr1, pswz, pls, qf0, qf1, m_run, l_run, o);
    else
      attn_tile<true>(Kb, Vb, t * 64, qg, g, sadr0, sadr1, pswz, pls, qf0, qf1, m_run, l_run, o);
    __builtin_amdgcn_sched_barrier(0);
    __builtin_amdgcn_s_barrier();
  }

  const float inv = 1.0f / l_run;
  const size_t obase = ((size_t)bb * SEQ + q0 + qloc) * EMB + (size_t)h * HDIM + g * 4;
  #pragma unroll
  for (int nf = 0; nf < 4; ++nf) {
    s16x4 pk;
    #pragma unroll
    for (int j = 0; j < 4; ++j) pk[j] = f2bf(o[nf][j] * inv);
    *(s16x4*)(ao + obase + nf * 16) = pk;
  }
}

// ---------------- output GEMM + bias ----------------
#define OUT_NN 16   // 1024/64

__global__ __launch_bounds__(256, 4) void out_kernel(
    const short* __restrict__ ab, const short* __restrict__ wb,
    const float* __restrict__ bias, float* __restrict__ out) {
  __shared__ __align__(16) short ls[16384];
  f32x4 acc[2][2];
  const int nwg = 64 * OUT_NN;                       // 1024, %8 == 0
  const int wg = (blockIdx.x & 7) * (nwg >> 3) + (blockIdx.x >> 3);  // XCD swizzle
  const int m0 = (wg >> 4) * 64, n0 = (wg & 15) * 64;
  gemm_mainloop64(ab, wb, m0, n0, ls, acc);

  const int w = threadIdx.x >> 6, lane = threadIdx.x & 63;
  const int wm = w >> 1, wn = w & 1;
  const int colb = n0 + wn * 32 + (lane & 15);
  const int rowb = m0 + wm * 32 + ((lane >> 4) << 2);
  #pragma unroll
  for (int ni = 0; ni < 2; ++ni) {
    const int col = colb + ni * 16;
    const float bv = bias[col];
    #pragma unroll
    for (int mi = 0; mi < 2; ++mi)
      #pragma unroll
      for (int j = 0; j < 4; ++j) {
        const int m = rowb + mi * 16 + j;
        out[(size_t)m * EMB + col] = acc[mi][ni][j] + bv;
      }
  }
}

// ---------------- launch ----------------
extern "C" void kernel_launch(void* const* d_in, const int* in_sizes, int n_in,
                              void* d_out, int out_size, void* d_ws, size_t ws_size,
                              hipStream_t stream) {
  const float* x    = (const float*)d_in[0];
  const float* qkvw = (const float*)d_in[1];
  const float* qkvb = (const float*)d_in[2];
  const float* outw = (const float*)d_in[3];
  const float* outb = (const float*)d_in[4];
  float* out = (float*)d_out;
  char* ws = (char*)d_ws;

  short* xb    = (short*)(ws + 0);            // 4096x1024 bf16 — reused as attn_out
  short* wqkvb = (short*)(ws + 8388608);      // 1152x1024 bf16
  short* woutb = (short*)(ws + 10747904);     // 1024x1024 bf16
  float* cost  = (float*)(ws + 12845056);     // 2048x32 f32
  float* sint  = (float*)(ws + 13107200);
  short* qbuf  = (short*)(ws + 13369344);     // [B][H][S][D] bf16, q pre-scaled
  short* kbuf  = (short*)(ws + 21757952);     // [B][S][D] bf16
  short* vtb   = (short*)(ws + 22282240);     // [B][D][S] bf16 (transposed)
  short* aob   = xb;

  prep_kernel<<<3168, 256, 0, stream>>>(x, qkvw, outw, xb, wqkvb, woutb, cost, sint);
  qkv_kernel<<<1152, 256, 0, stream>>>(xb, wqkvb, qkvb, cost, sint, qbuf, kbuf, vtb);
  attn_kernel<<<dim3(32, 32), 256, 0, stream>>>(qbuf, kbuf, vtb, aob);
  out_kernel<<<1024, 256, 0, stream>>>(aob, woutb, outb, out);
}